// Round 3
// baseline (1258.731 us; speedup 1.0000x reference)
//
#include <hip/hip_runtime.h>

#define SCALE 0.1f
#define LN_EPS 1e-5f
#define TPB 512
#define NBLOCKS 1024            // 1024 blocks * 8 waves * 2 iters * 2 rows = 32768

#define BF_LO(u) __uint_as_float((u) << 16)
#define BF_HI(u) __uint_as_float((u) & 0xffff0000u)

__device__ inline unsigned bfpack(float lo, float hi) {
    unsigned ul = __float_as_uint(lo), uh = __float_as_uint(hi);
    ul = (ul + 0x7fffu + ((ul >> 16) & 1u)) >> 16;
    uh = (uh + 0x7fffu + ((uh >> 16) & 1u)) >> 16;
    return ul | (uh << 16);
}
__device__ inline float bfround(float v) {
    unsigned u = __float_as_uint(v);
    u = (u + 0x7fffu + ((u >> 16) & 1u)) & 0xffff0000u;
    return __uint_as_float(u);
}

// Prepacked weights in device globals (rewritten by prep every launch).
// Granule layout: gid = (e*2 + h)*64 + l; lane l's element e maps to
// D = 256*(e>>2) + 4*l + (e&3); h = k-half. uint4 = 8 bf16, k ascending.
__device__ uint4 g_wd[1536];    // gamma ⊙ w_down (bf16 pairs)
__device__ uint4 g_wu[1536];    // SCALE * w_up^T (bf16 pairs)
__device__ float g_B[16];       // sum_D bf16(gamma*wd)[D][k]
__device__ float g_C[16];       // sum_D beta[D]*wd[D][k] + b_down[k]

__global__ __launch_bounds__(256)
void prep(const float* __restrict__ gamma, const float* __restrict__ beta,
          const float* __restrict__ w_down, const float* __restrict__ b_down,
          const float* __restrict__ w_up)
{
    const int t = threadIdx.x;
    #pragma unroll
    for (int s = 0; s < 6; ++s) {
        const int gid = t + 256 * s;        // [0,1536)
        const int l   = gid & 63;
        const int top = gid >> 6;
        const int h   = top & 1;
        const int e   = top >> 1;
        const int D   = 256 * (e >> 2) + 4 * l + (e & 3);
        const float gm = gamma[D];
        const float4 w0 = *(const float4*)(w_down + D * 16 + 8 * h);
        const float4 w1 = *(const float4*)(w_down + D * 16 + 8 * h + 4);
        uint4 pd;
        pd.x = bfpack(w0.x * gm, w0.y * gm);
        pd.y = bfpack(w0.z * gm, w0.w * gm);
        pd.z = bfpack(w1.x * gm, w1.y * gm);
        pd.w = bfpack(w1.z * gm, w1.w * gm);
        g_wd[gid] = pd;
        const int kb = 8 * h;
        uint4 pu;
        pu.x = bfpack(SCALE * w_up[(kb+0)*768 + D], SCALE * w_up[(kb+1)*768 + D]);
        pu.y = bfpack(SCALE * w_up[(kb+2)*768 + D], SCALE * w_up[(kb+3)*768 + D]);
        pu.z = bfpack(SCALE * w_up[(kb+4)*768 + D], SCALE * w_up[(kb+5)*768 + D]);
        pu.w = bfpack(SCALE * w_up[(kb+6)*768 + D], SCALE * w_up[(kb+7)*768 + D]);
        g_wu[gid] = pu;
    }
    // B_k, C_k
    __shared__ float sB[16][16];
    __shared__ float sC[16][16];
    const int k = t & 15, c = t >> 4;       // 16 chunks of 48 D
    float pb = 0.f, pc = 0.f;
    for (int m = 0; m < 48; ++m) {
        const int D = c * 48 + m;
        const float w = w_down[D * 16 + k];
        pb += bfround(gamma[D] * w);
        pc = fmaf(beta[D], w, pc);
    }
    sB[c][k] = pb; sC[c][k] = pc;
    __syncthreads();
    if (t < 16) {
        float b = 0.f, cc = 0.f;
        #pragma unroll
        for (int i = 0; i < 16; ++i) { b += sB[i][t]; cc += sC[i][t]; }
        g_B[t] = b;
        g_C[t] = cc + b_down[t];
    }
}

// Down-phase: k pairs into accumulators (2 rows share the unpack)
#define DUO(u, k0)                                                    \
    { float wl = BF_LO(u), wh = BF_HI(u);                             \
      aA[k0] = fmaf(wl, va, aA[k0]); aB[k0] = fmaf(wl, vb, aB[k0]);   \
      aA[(k0)+1] = fmaf(wh, va, aA[(k0)+1]);                          \
      aB[(k0)+1] = fmaf(wh, vb, aB[(k0)+1]); }

#define UPD(u, k0)                                                    \
    { float wl = BF_LO(u), wh = BF_HI(u);                             \
      uA = fmaf(wl, dnA[k0], uA); uB = fmaf(wl, dnB[k0], uB);         \
      uA = fmaf(wh, dnA[(k0)+1], uA); uB = fmaf(wh, dnB[(k0)+1], uB); }

__global__ __launch_bounds__(TPB, 2)
void adapter_main(const float* __restrict__ x,
                  const float* __restrict__ b_up,
                  float* __restrict__ out)
{
    __shared__ uint4 s_wd[1536];   // 24 KB
    __shared__ uint4 s_wu[1536];   // 24 KB
    __shared__ float s_BC[32];

    const int t    = threadIdx.x;
    const int lane = t & 63;
    const int wave = t >> 6;

    #pragma unroll
    for (int s = 0; s < 3; ++s) {
        s_wd[t + TPB * s] = g_wd[t + TPB * s];
        s_wu[t + TPB * s] = g_wu[t + TPB * s];
    }
    if (t < 32) s_BC[t] = (t < 16) ? g_B[t] : g_C[t - 16];
    __syncthreads();

    const float Bk = s_BC[lane & 15];
    const float Ck = s_BC[16 + (lane & 15)];

    float bu[12];                 // pre-scaled b_up
    #pragma unroll
    for (int j = 0; j < 3; ++j) {
        float4 b4 = *(const float4*)(b_up + 256 * j + 4 * lane);
        bu[4*j+0] = SCALE * b4.x; bu[4*j+1] = SCALE * b4.y;
        bu[4*j+2] = SCALE * b4.z; bu[4*j+3] = SCALE * b4.w;
    }
    const float inv_d = 1.0f / 768.0f;

    #pragma unroll 1
    for (int it = 0; it < 2; ++it) {
        const int row0 = (((blockIdx.x * 8 + wave) * 2) + it) * 2;
        const float* xr0 = x + (size_t)row0 * 768;
        const float* xr1 = xr0 + 768;

        float xa[12], xb[12];
        #pragma unroll
        for (int j = 0; j < 3; ++j) {
            *(float4*)&xa[4*j] = *(const float4*)(xr0 + 256*j + 4*lane);
            *(float4*)&xb[4*j] = *(const float4*)(xr1 + 256*j + 4*lane);
        }

        float s1a = 0.f, s2a = 0.f, s1b = 0.f, s2b = 0.f;
        float aA[16], aB[16];
        #pragma unroll
        for (int k = 0; k < 16; ++k) { aA[k] = 0.f; aB[k] = 0.f; }

        #pragma unroll
        for (int e = 0; e < 12; ++e) {
            const float va = xa[e], vb = xb[e];
            s1a += va; s2a = fmaf(va, va, s2a);
            s1b += vb; s2b = fmaf(vb, vb, s2b);
            const int gb = e * 128 + lane;
            const uint4 W0 = s_wd[gb];
            const uint4 W1 = s_wd[gb + 64];
            DUO(W0.x, 0)  DUO(W0.y, 2)  DUO(W0.z, 4)  DUO(W0.w, 6)
            DUO(W1.x, 8)  DUO(W1.y, 10) DUO(W1.z, 12) DUO(W1.w, 14)
        }

        // split-butterfly: 16-vector across 16 lanes
        #pragma unroll
        for (int m = 8; m >= 1; m >>= 1) {
            const bool up = (lane & m) != 0;
            #pragma unroll
            for (int i = 0; i < m; ++i) {
                float sa = up ? aA[i] : aA[i+m];
                float ra = __shfl_xor(sa, m, 64);
                aA[i] = (up ? aA[i+m] : aA[i]) + ra;
                float sb = up ? aB[i] : aB[i+m];
                float rb = __shfl_xor(sb, m, 64);
                aB[i] = (up ? aB[i+m] : aB[i]) + rb;
            }
        }
        float vA = aA[0]; vA += __shfl_xor(vA, 16, 64); vA += __shfl_xor(vA, 32, 64);
        float vB = aB[0]; vB += __shfl_xor(vB, 16, 64); vB += __shfl_xor(vB, 32, 64);
        #pragma unroll
        for (int m = 32; m >= 1; m >>= 1) {
            s1a += __shfl_xor(s1a, m, 64); s2a += __shfl_xor(s2a, m, 64);
            s1b += __shfl_xor(s1b, m, 64); s2b += __shfl_xor(s2b, m, 64);
        }

        const float meanA = s1a * inv_d;
        const float rsA   = rsqrtf(fmaf(s2a, inv_d, -(meanA*meanA)) + LN_EPS);
        const float meanB = s1b * inv_d;
        const float rsB   = rsqrtf(fmaf(s2b, inv_d, -(meanB*meanB)) + LN_EPS);
        const float dva = fmaxf(fmaf(rsA, fmaf(-meanA, Bk, vA), Ck), 0.f);
        const float dvb = fmaxf(fmaf(rsB, fmaf(-meanB, Bk, vB), Ck), 0.f);

        float dnA[16], dnB[16];
        #pragma unroll
        for (int k = 0; k < 16; ++k) {
            dnA[k] = __shfl(dva, k, 64);
            dnB[k] = __shfl(dvb, k, 64);
        }

        // up-proj (weights pre-scaled): store each float4 group immediately
        float* or0 = out + (size_t)row0 * 768;
        float* or1 = or0 + 768;
        #pragma unroll
        for (int j = 0; j < 3; ++j) {
            float oa[4], ob[4];
            #pragma unroll
            for (int i = 0; i < 4; ++i) {
                const int e = 4*j + i;
                const int gb = e * 128 + lane;
                const uint4 U0 = s_wu[gb];
                const uint4 U1 = s_wu[gb + 64];
                float uA = 0.f, uB = 0.f;
                UPD(U0.x, 0)  UPD(U0.y, 2)  UPD(U0.z, 4)  UPD(U0.w, 6)
                UPD(U1.x, 8)  UPD(U1.y, 10) UPD(U1.z, 12) UPD(U1.w, 14)
                oa[i] = xa[e] + (uA + bu[e]);
                ob[i] = xb[e] + (uB + bu[e]);
            }
            *(float4*)(or0 + 256*j + 4*lane) = *(const float4*)oa;
            *(float4*)(or1 + 256*j + 4*lane) = *(const float4*)ob;
        }
    }
}

extern "C" void kernel_launch(void* const* d_in, const int* in_sizes, int n_in,
                              void* d_out, int out_size, void* d_ws, size_t ws_size,
                              hipStream_t stream) {
    const float* x      = (const float*)d_in[0];
    const float* gamma  = (const float*)d_in[1];
    const float* beta   = (const float*)d_in[2];
    const float* w_down = (const float*)d_in[3];
    const float* b_down = (const float*)d_in[4];
    const float* w_up   = (const float*)d_in[5];
    const float* b_up   = (const float*)d_in[6];
    float* out = (float*)d_out;

    prep<<<1, 256, 0, stream>>>(gamma, beta, w_down, b_down, w_up);
    adapter_main<<<NBLOCKS, TPB, 0, stream>>>(x, b_up, out);
}

// Round 4
// 886.674 us; speedup vs baseline: 1.4196x; 1.4196x over previous
//
#include <hip/hip_runtime.h>

#define SCALE 0.1f
#define LN_EPS 1e-5f
#define TPB 512                 // 8 waves
#define NBLOCKS 1024            // 1024 * 8 waves * 4 rows/wave = 32768 rows

#define BF_LO(u) __uint_as_float((u) << 16)
#define BF_HI(u) __uint_as_float((u) & 0xffff0000u)

__device__ inline unsigned bfpack(float lo, float hi) {
    unsigned ul = __float_as_uint(lo), uh = __float_as_uint(hi);
    ul = (ul + 0x7fffu + ((ul >> 16) & 1u)) >> 16;
    uh = (uh + 0x7fffu + ((uh >> 16) & 1u)) >> 16;
    return ul | (uh << 16);
}
__device__ inline float bfround(float v) {
    unsigned u = __float_as_uint(v);
    u = (u + 0x7fffu + ((u >> 16) & 1u)) & 0xffff0000u;
    return __uint_as_float(u);
}

// Prepacked weights in device globals (rewritten by prep every launch).
// Granule layout: gid = (e*2 + h)*64 + l; lane l's element e maps to
// D = 256*(e>>2) + 4*l + (e&3); h = k-half. uint4 = 8 bf16, k ascending.
__device__ uint4 g_wd[1536];    // gamma ⊙ w_down (bf16 pairs)
__device__ uint4 g_wu[1536];    // SCALE * w_up^T (bf16 pairs)
__device__ float g_B[16];       // sum_D bf16(gamma*wd)[D][k]
__device__ float g_C[16];       // sum_D beta[D]*wd[D][k] + b_down[k]

__global__ __launch_bounds__(256)
void prep(const float* __restrict__ gamma, const float* __restrict__ beta,
          const float* __restrict__ w_down, const float* __restrict__ b_down,
          const float* __restrict__ w_up)
{
    const int t = threadIdx.x;
    #pragma unroll
    for (int s = 0; s < 6; ++s) {
        const int gid = t + 256 * s;        // [0,1536)
        const int l   = gid & 63;
        const int top = gid >> 6;
        const int h   = top & 1;
        const int e   = top >> 1;
        const int D   = 256 * (e >> 2) + 4 * l + (e & 3);
        const float gm = gamma[D];
        const float4 w0 = *(const float4*)(w_down + D * 16 + 8 * h);
        const float4 w1 = *(const float4*)(w_down + D * 16 + 8 * h + 4);
        uint4 pd;
        pd.x = bfpack(w0.x * gm, w0.y * gm);
        pd.y = bfpack(w0.z * gm, w0.w * gm);
        pd.z = bfpack(w1.x * gm, w1.y * gm);
        pd.w = bfpack(w1.z * gm, w1.w * gm);
        g_wd[gid] = pd;
        const int kb = 8 * h;
        uint4 pu;
        pu.x = bfpack(SCALE * w_up[(kb+0)*768 + D], SCALE * w_up[(kb+1)*768 + D]);
        pu.y = bfpack(SCALE * w_up[(kb+2)*768 + D], SCALE * w_up[(kb+3)*768 + D]);
        pu.z = bfpack(SCALE * w_up[(kb+4)*768 + D], SCALE * w_up[(kb+5)*768 + D]);
        pu.w = bfpack(SCALE * w_up[(kb+6)*768 + D], SCALE * w_up[(kb+7)*768 + D]);
        g_wu[gid] = pu;
    }
    // B_k, C_k
    __shared__ float sB[16][16];
    __shared__ float sC[16][16];
    const int k = t & 15, c = t >> 4;       // 16 chunks of 48 D
    float pb = 0.f, pc = 0.f;
    for (int m = 0; m < 48; ++m) {
        const int D = c * 48 + m;
        const float w = w_down[D * 16 + k];
        pb += bfround(gamma[D] * w);
        pc = fmaf(beta[D], w, pc);
    }
    sB[c][k] = pb; sC[c][k] = pc;
    __syncthreads();
    if (t < 16) {
        float b = 0.f, cc = 0.f;
        #pragma unroll
        for (int i = 0; i < 16; ++i) { b += sB[i][t]; cc += sC[i][t]; }
        g_B[t] = b;
        g_C[t] = cc + b_down[t];
    }
}

// Down-phase: one row, k-pair into accumulators
#define DN(u, k0)                                                     \
    { float wl = BF_LO(u), wh = BF_HI(u);                             \
      aA[k0] = fmaf(wl, va, aA[k0]);                                  \
      aA[(k0)+1] = fmaf(wh, va, aA[(k0)+1]); }

// Up-phase: dot with wave-uniform (SGPR) dn values
#define UP(u, k0)                                                     \
    { float wl = BF_LO(u), wh = BF_HI(u);                             \
      uA = fmaf(wl, dn[k0], uA);                                      \
      uA = fmaf(wh, dn[(k0)+1], uA); }

__global__ __launch_bounds__(TPB)
void adapter_main(const float* __restrict__ x,
                  const float* __restrict__ b_up,
                  float* __restrict__ out)
{
    __shared__ uint4 s_wd[1536];   // 24 KB
    __shared__ uint4 s_wu[1536];   // 24 KB
    __shared__ float s_BC[32];

    const int t    = threadIdx.x;
    const int lane = t & 63;
    const int wave = t >> 6;

    #pragma unroll
    for (int s = 0; s < 3; ++s) {
        s_wd[t + TPB * s] = g_wd[t + TPB * s];
        s_wu[t + TPB * s] = g_wu[t + TPB * s];
    }
    if (t < 32) s_BC[t] = (t < 16) ? g_B[t] : g_C[t - 16];
    __syncthreads();

    const float Bk = s_BC[lane & 15];
    const float Ck = s_BC[16 + (lane & 15)];

    float bu[12];                 // pre-scaled b_up
    #pragma unroll
    for (int j = 0; j < 3; ++j) {
        float4 b4 = *(const float4*)(b_up + 256 * j + 4 * lane);
        bu[4*j+0] = SCALE * b4.x; bu[4*j+1] = SCALE * b4.y;
        bu[4*j+2] = SCALE * b4.z; bu[4*j+3] = SCALE * b4.w;
    }
    const float inv_d = 1.0f / 768.0f;

    #pragma unroll 1
    for (int r = 0; r < 4; ++r) {
        const int row = blockIdx.x * 32 + wave * 4 + r;
        const float* xr = x + (size_t)row * 768;

        float xa[12];
        #pragma unroll
        for (int j = 0; j < 3; ++j)
            *(float4*)&xa[4*j] = *(const float4*)(xr + 256*j + 4*lane);

        float s1 = 0.f, s2 = 0.f;
        float aA[16];
        #pragma unroll
        for (int k = 0; k < 16; ++k) aA[k] = 0.f;

        #pragma unroll
        for (int e = 0; e < 12; ++e) {
            const float va = xa[e];
            s1 += va; s2 = fmaf(va, va, s2);
            const int gb = e * 128 + lane;
            const uint4 W0 = s_wd[gb];
            const uint4 W1 = s_wd[gb + 64];
            DN(W0.x, 0)  DN(W0.y, 2)  DN(W0.z, 4)  DN(W0.w, 6)
            DN(W1.x, 8)  DN(W1.y, 10) DN(W1.z, 12) DN(W1.w, 14)
        }

        // split-butterfly: 16-vector reduced across each 16-lane group
        #pragma unroll
        for (int m = 8; m >= 1; m >>= 1) {
            const bool up = (lane & m) != 0;
            #pragma unroll
            for (int i = 0; i < m; ++i) {
                float sa = up ? aA[i] : aA[i+m];
                float ra = __shfl_xor(sa, m, 64);
                aA[i] = (up ? aA[i+m] : aA[i]) + ra;
            }
        }
        float vA = aA[0];
        vA += __shfl_xor(vA, 16, 64);
        vA += __shfl_xor(vA, 32, 64);
        #pragma unroll
        for (int m = 32; m >= 1; m >>= 1) {
            s1 += __shfl_xor(s1, m, 64);
            s2 += __shfl_xor(s2, m, 64);
        }

        const float mean = s1 * inv_d;
        const float rs   = rsqrtf(fmaf(s2, inv_d, -(mean*mean)) + LN_EPS);
        const float dva  = fmaxf(fmaf(rs, fmaf(-mean, Bk, vA), Ck), 0.f);

        // broadcast down vector: literal-lane shfl -> v_readlane -> SGPRs
        float dn[16];
        #pragma unroll
        for (int k = 0; k < 16; ++k) dn[k] = __shfl(dva, k, 64);

        // up-proj (weights pre-scaled by SCALE) + residual, store per float4
        float* orow = out + (size_t)row * 768;
        #pragma unroll
        for (int j = 0; j < 3; ++j) {
            float oa[4];
            #pragma unroll
            for (int i = 0; i < 4; ++i) {
                const int e = 4*j + i;
                const int gb = e * 128 + lane;
                const uint4 U0 = s_wu[gb];
                const uint4 U1 = s_wu[gb + 64];
                float uA = 0.f;
                UP(U0.x, 0)  UP(U0.y, 2)  UP(U0.z, 4)  UP(U0.w, 6)
                UP(U1.x, 8)  UP(U1.y, 10) UP(U1.z, 12) UP(U1.w, 14)
                oa[i] = xa[e] + (uA + bu[e]);
            }
            *(float4*)(orow + 256*j + 4*lane) = *(const float4*)oa;
        }
    }
}

extern "C" void kernel_launch(void* const* d_in, const int* in_sizes, int n_in,
                              void* d_out, int out_size, void* d_ws, size_t ws_size,
                              hipStream_t stream) {
    const float* x      = (const float*)d_in[0];
    const float* gamma  = (const float*)d_in[1];
    const float* beta   = (const float*)d_in[2];
    const float* w_down = (const float*)d_in[3];
    const float* b_down = (const float*)d_in[4];
    const float* w_up   = (const float*)d_in[5];
    const float* b_up   = (const float*)d_in[6];
    float* out = (float*)d_out;

    prep<<<1, 256, 0, stream>>>(gamma, beta, w_down, b_down, w_up);
    adapter_main<<<NBLOCKS, TPB, 0, stream>>>(x, b_up, out);
}